// Round 1
// baseline (1092.703 us; speedup 1.0000x reference)
//
#include <hip/hip_runtime.h>

#define B_ 512
#define Q_ 32768
#define D_ 256
#define L_ 32769  // 1 + Q

#define BM 128
#define BN 128
#define BK 32

typedef __attribute__((ext_vector_type(8))) short short8;
typedef __attribute__((ext_vector_type(4))) float f32x4;

// round-to-nearest-even fp32 -> bf16 bits (truncation would bias dot by ~2^-8 and FAIL accuracy)
__device__ __forceinline__ unsigned int f2bf1(float f) {
    unsigned int u = __float_as_uint(f);
    return (u + 0x7FFFu + ((u >> 16) & 1u)) >> 16;
}
__device__ __forceinline__ unsigned int f2bf2(float lo, float hi) {
    return f2bf1(lo) | (f2bf1(hi) << 16);
}

// ---------------- prep: per-row norms -> scales, and the self-dot column (fp32 exact) ----------------
__global__ void prep_kernel(const float* __restrict__ x0, const float* __restrict__ x1,
                            const float* __restrict__ x2, const float* __restrict__ x3,
                            float* __restrict__ out0, float* __restrict__ scales) {
    const int ci[8] = {0, 0, 0, 1, 1, 2, 2, 3};
    const int cj[8] = {1, 2, 3, 0, 2, 0, 1, 0};
    const float* xs[4] = {x0, x1, x2, x3};
    int c = blockIdx.x;
    const float* xi = xs[ci[c]];
    const float* xj = xs[cj[c]];
    int wave = threadIdx.x >> 6;
    int lane = threadIdx.x & 63;

    for (int b = wave; b < B_; b += 4) {
        float4 a = ((const float4*)(xi + b * D_))[lane];
        float4 bb = ((const float4*)(xj + b * D_))[lane];
        float dot = a.x * bb.x + a.y * bb.y + a.z * bb.z + a.w * bb.w;
        float ni = a.x * a.x + a.y * a.y + a.z * a.z + a.w * a.w;
        float nj = bb.x * bb.x + bb.y * bb.y + bb.z * bb.z + bb.w * bb.w;
        for (int off = 32; off; off >>= 1) {
            dot += __shfl_down(dot, off);
            ni  += __shfl_down(ni, off);
            nj  += __shfl_down(nj, off);
        }
        if (lane == 0) {
            float s = 1.0f / (sqrtf(ni) * sqrtf(nj) * 0.07f);
            scales[c * B_ + b] = s;
            out0[(size_t)(c * B_ + b) * L_] = __expf(dot * s);
        }
    }
}

// ---------------- GEMM: out0[c][b][1+q] = exp(<x_i[b], mem_j[q]> * scale[c][b]) ----------------
__global__ __launch_bounds__(256) void gemm_kernel(
    const float* __restrict__ x0, const float* __restrict__ x1,
    const float* __restrict__ x2, const float* __restrict__ x3,
    const float* __restrict__ m0p, const float* __restrict__ m1p,
    const float* __restrict__ m2p, const float* __restrict__ m3p,
    const float* __restrict__ scales, float* __restrict__ out0) {
    const int ci[8] = {0, 0, 0, 1, 1, 2, 2, 3};
    const int cj[8] = {1, 2, 3, 0, 2, 0, 1, 0};
    const float* xs[4] = {x0, x1, x2, x3};
    const float* ms[4] = {m0p, m1p, m2p, m3p};

    const int c = blockIdx.z;
    const float* A = xs[ci[c]];
    const float* Bm = ms[cj[c]];
    const int m0 = blockIdx.y * BM;
    const int n0 = blockIdx.x * BN;

    __shared__ unsigned short As[BM * BK];
    __shared__ unsigned short Bs[BN * BK];

    const int tid = threadIdx.x;
    const int lane = tid & 63;
    const int wave = tid >> 6;
    const int wm = (wave & 1) * 64;
    const int wn = (wave >> 1) * 64;
    const int q4 = lane >> 4;
    const int l15 = lane & 15;

    // staging assignment: thread t stages 16 floats of A row (t>>1) and B row (t>>1)
    const int srow = tid >> 1;
    const int scol = (tid & 1) * 16;

    f32x4 acc[4][4];
    for (int mt = 0; mt < 4; mt++)
        for (int nt = 0; nt < 4; nt++)
            acc[mt][nt] = (f32x4){0.f, 0.f, 0.f, 0.f};

    const float* gA = A + (size_t)(m0 + srow) * D_ + scol;
    const float* gB = Bm + (size_t)(n0 + srow) * D_ + scol;
    unsigned int* wA = (unsigned int*)&As[srow * BK + scol];
    unsigned int* wB = (unsigned int*)&Bs[srow * BK + scol];

    for (int k0 = 0; k0 < D_; k0 += BK) {
        float4 a0 = *(const float4*)(gA + k0);
        float4 a1 = *(const float4*)(gA + k0 + 4);
        float4 a2 = *(const float4*)(gA + k0 + 8);
        float4 a3 = *(const float4*)(gA + k0 + 12);
        float4 b0 = *(const float4*)(gB + k0);
        float4 b1 = *(const float4*)(gB + k0 + 4);
        float4 b2 = *(const float4*)(gB + k0 + 8);
        float4 b3 = *(const float4*)(gB + k0 + 12);
        __syncthreads();  // previous iter's LDS reads done before overwrite
        wA[0] = f2bf2(a0.x, a0.y); wA[1] = f2bf2(a0.z, a0.w);
        wA[2] = f2bf2(a1.x, a1.y); wA[3] = f2bf2(a1.z, a1.w);
        wA[4] = f2bf2(a2.x, a2.y); wA[5] = f2bf2(a2.z, a2.w);
        wA[6] = f2bf2(a3.x, a3.y); wA[7] = f2bf2(a3.z, a3.w);
        wB[0] = f2bf2(b0.x, b0.y); wB[1] = f2bf2(b0.z, b0.w);
        wB[2] = f2bf2(b1.x, b1.y); wB[3] = f2bf2(b1.z, b1.w);
        wB[4] = f2bf2(b2.x, b2.y); wB[5] = f2bf2(b2.z, b2.w);
        wB[6] = f2bf2(b3.x, b3.y); wB[7] = f2bf2(b3.z, b3.w);
        __syncthreads();

        short8 af[4], bf[4];
        for (int mt = 0; mt < 4; mt++)
            af[mt] = *(const short8*)&As[(wm + mt * 16 + l15) * BK + q4 * 8];
        for (int nt = 0; nt < 4; nt++)
            bf[nt] = *(const short8*)&Bs[(wn + nt * 16 + l15) * BK + q4 * 8];
        for (int mt = 0; mt < 4; mt++)
            for (int nt = 0; nt < 4; nt++)
                acc[mt][nt] = __builtin_amdgcn_mfma_f32_16x16x32_bf16(
                    af[mt], bf[nt], acc[mt][nt], 0, 0, 0);
    }

    // epilogue: C/D layout col = lane&15, row = (lane>>4)*4 + reg   [verified m89/m91]
    for (int mt = 0; mt < 4; mt++) {
        int gr = m0 + wm + mt * 16 + q4 * 4;
        float s0 = scales[c * B_ + gr + 0];
        float s1 = scales[c * B_ + gr + 1];
        float s2 = scales[c * B_ + gr + 2];
        float s3 = scales[c * B_ + gr + 3];
        size_t rowbase = (size_t)(c * B_ + gr) * L_ + 1;
        for (int nt = 0; nt < 4; nt++) {
            int gc = n0 + wn + nt * 16 + l15;
            f32x4 v = acc[mt][nt];
            out0[rowbase + gc]          = __expf(v.x * s0);
            out0[rowbase + L_ + gc]     = __expf(v.y * s1);
            out0[rowbase + 2 * L_ + gc] = __expf(v.z * s2);
            out0[rowbase + 3 * L_ + gc] = __expf(v.w * s3);
        }
    }
}

// ---------------- FIFO shift: new_mem[v] = concat(mem_v[512:], y_v) ----------------
__global__ void shift_kernel(const float4* __restrict__ mm0, const float4* __restrict__ mm1,
                             const float4* __restrict__ mm2, const float4* __restrict__ mm3,
                             const float4* __restrict__ yy0, const float4* __restrict__ yy1,
                             const float4* __restrict__ yy2, const float4* __restrict__ yy3,
                             float4* __restrict__ out1) {
    const float4* mems[4] = {mm0, mm1, mm2, mm3};
    const float4* ys[4] = {yy0, yy1, yy2, yy3};
    const int per_view = Q_ * D_ / 4;          // 2,097,152 float4
    const int boundary = (Q_ - B_) * D_ / 4;   // 2,064,384
    const int shift = B_ * D_ / 4;             // 32,768
    const int total = 4 * per_view;
    for (int idx = blockIdx.x * blockDim.x + threadIdx.x; idx < total;
         idx += gridDim.x * blockDim.x) {
        int v = idx >> 21;
        int rem = idx & (per_view - 1);
        float4 val = (rem < boundary) ? mems[v][rem + shift] : ys[v][rem - boundary];
        out1[idx] = val;
    }
}

extern "C" void kernel_launch(void* const* d_in, const int* in_sizes, int n_in,
                              void* d_out, int out_size, void* d_ws, size_t ws_size,
                              hipStream_t stream) {
    const float* x[4];
    const float* y[4];
    const float* mem[4];
    // setup_inputs() dict order: x0,y0,mem0, x1,y1,mem1, ... ; fall back to
    // signature order (x0..x3,y0..y3,mem0..3) if sizes say otherwise.
    bool dict_order = (n_in >= 3) && (in_sizes[2] == Q_ * D_);
    for (int v = 0; v < 4; v++) {
        if (dict_order) {
            x[v] = (const float*)d_in[3 * v];
            y[v] = (const float*)d_in[3 * v + 1];
            mem[v] = (const float*)d_in[3 * v + 2];
        } else {
            x[v] = (const float*)d_in[v];
            y[v] = (const float*)d_in[4 + v];
            mem[v] = (const float*)d_in[8 + v];
        }
    }
    float* out0 = (float*)d_out;
    float* out1 = out0 + (size_t)8 * B_ * L_;
    float* scales = (float*)d_ws;  // 8*512 floats = 16 KB

    prep_kernel<<<8, 256, 0, stream>>>(x[0], x[1], x[2], x[3], out0, scales);

    dim3 grid(Q_ / BN, B_ / BM, 8);
    gemm_kernel<<<grid, 256, 0, stream>>>(x[0], x[1], x[2], x[3],
                                          mem[0], mem[1], mem[2], mem[3],
                                          scales, out0);

    shift_kernel<<<4096, 256, 0, stream>>>(
        (const float4*)mem[0], (const float4*)mem[1], (const float4*)mem[2], (const float4*)mem[3],
        (const float4*)y[0], (const float4*)y[1], (const float4*)y[2], (const float4*)y[3],
        (float4*)out1);
}